// Round 1
// baseline (3400.094 us; speedup 1.0000x reference)
//
#include <hip/hip_runtime.h>
#include <math.h>

constexpr int Bb  = 64;
constexpr int Tt  = 2048;
constexpr int INN = 128;
constexpr int HH  = 256;
constexpr int ROWS = Bb * Tt;   // 131072

// ---------------------------------------------------------------------------
// GEMM: out[row][j] = sum_k in[row][k] * W[j][k] + bias1[j] + bias2[j]
// rows = B*T, j < 256, K in {128, 256}. Tile: 64 rows x 256 cols, Kc=16,
// 256 threads, 8x8 register tile per thread.
// In-place safe when in == out: a WG reads its 64 rows fully (all K) inside
// the k-loop and only writes those same rows in the epilogue; it owns ALL
// 256 output cols of those rows, so no cross-WG hazard.
// ---------------------------------------------------------------------------
template <int K>
__global__ __launch_bounds__(256) void ih_gemm(const float* in, const float* W,
                                               const float* bias1, const float* bias2,
                                               float* out)
{
    __shared__ float a_lds[16][68];    // [kk][row]   (+4 pad)
    __shared__ float b_lds[16][264];   // [kk][col]   (+8 pad)

    const int tid = threadIdx.x;
    const int tx  = tid & 31;   // col group: cols tx*8 .. +8
    const int ty  = tid >> 5;   // row group: rows ty*8 .. +8
    const int row0 = blockIdx.x * 64;

    float acc[8][8];
#pragma unroll
    for (int r = 0; r < 8; ++r)
#pragma unroll
        for (int c = 0; c < 8; ++c) acc[r][c] = 0.f;

    for (int k0 = 0; k0 < K; k0 += 16) {
        // stage A tile: 64 rows x 16 k  (1024 elems, 4 per thread)
#pragma unroll
        for (int i = 0; i < 4; ++i) {
            int e = i * 256 + tid;
            int r = e >> 4, kk = e & 15;
            a_lds[kk][r] = in[(row0 + r) * K + k0 + kk];
        }
        // stage B tile: 256 cols x 16 k (4096 elems, 16 per thread)
#pragma unroll
        for (int i = 0; i < 16; ++i) {
            int e = i * 256 + tid;
            int j = e >> 4, kk = e & 15;
            b_lds[kk][j] = W[j * K + k0 + kk];
        }
        __syncthreads();

#pragma unroll
        for (int kk = 0; kk < 16; ++kk) {
            float4 a0 = *(const float4*)&a_lds[kk][ty * 8];
            float4 a1 = *(const float4*)&a_lds[kk][ty * 8 + 4];
            float4 b0 = *(const float4*)&b_lds[kk][tx * 8];
            float4 b1 = *(const float4*)&b_lds[kk][tx * 8 + 4];
            float av[8] = {a0.x, a0.y, a0.z, a0.w, a1.x, a1.y, a1.z, a1.w};
            float bv[8] = {b0.x, b0.y, b0.z, b0.w, b1.x, b1.y, b1.z, b1.w};
#pragma unroll
            for (int r = 0; r < 8; ++r)
#pragma unroll
                for (int c = 0; c < 8; ++c)
                    acc[r][c] += av[r] * bv[c];
        }
        __syncthreads();
    }

    // epilogue: add biases, write 8x8 tile
    float bsum[8];
#pragma unroll
    for (int c = 0; c < 8; ++c) {
        int j = tx * 8 + c;
        bsum[c] = bias1[j] + bias2[j];
    }
#pragma unroll
    for (int r = 0; r < 8; ++r) {
        int row = row0 + ty * 8 + r;
        float4 o0 = make_float4(acc[r][0] + bsum[0], acc[r][1] + bsum[1],
                                acc[r][2] + bsum[2], acc[r][3] + bsum[3]);
        float4 o1 = make_float4(acc[r][4] + bsum[4], acc[r][5] + bsum[5],
                                acc[r][6] + bsum[6], acc[r][7] + bsum[7]);
        *(float4*)&out[row * HH + tx * 8]     = o0;
        *(float4*)&out[row * HH + tx * 8 + 4] = o1;
    }
}

// ---------------------------------------------------------------------------
// Recurrence: in-place over xp:  h_t = tanh(xp[t] + W_hh @ h_{t-1}),
// xp[b][t][:] is overwritten with h_t. One workgroup per batch, 1024 threads.
// Wave w (0..15) owns k-chunk [16w,16w+16)  -> h reads are wave-uniform
// broadcasts. Lane l owns outputs j = 4l..4l+3 (64 weights in VGPRs).
// Partials reduced through LDS by lanes tid<256. xp[t+1] prefetched one full
// step ahead to hide global latency.
// ---------------------------------------------------------------------------
__global__ __launch_bounds__(1024) void rnn_recur(float* xp, const float* Whh)
{
    constexpr int PS = HH + 4;     // 260, keeps float4 alignment (260 % 4 == 0)
    __shared__ float h_lds[HH];
    __shared__ float partial[16 * PS];

    const int tid = threadIdx.x;
    const int w   = tid >> 6;      // wave index = k-group
    const int l   = tid & 63;      // lane -> output group j = 4l..4l+3
    float* xpb = xp + (size_t)blockIdx.x * Tt * HH;

    // load weights: wreg[r][c] = Whh[(4l+r)*H + 16w + c]  (one-time, 64 VGPRs)
    float wreg[4][16];
#pragma unroll
    for (int r = 0; r < 4; ++r) {
        const float4* wp = (const float4*)&Whh[(4 * l + r) * HH + 16 * w];
#pragma unroll
        for (int q = 0; q < 4; ++q) {
            float4 v = wp[q];
            wreg[r][4 * q + 0] = v.x;
            wreg[r][4 * q + 1] = v.y;
            wreg[r][4 * q + 2] = v.z;
            wreg[r][4 * q + 3] = v.w;
        }
    }

    float xv = 0.f;
    if (tid < HH) {
        h_lds[tid] = 0.f;
        xv = xpb[tid];             // xp[t=0]
    }
    __syncthreads();

#pragma unroll 1
    for (int t = 0; t < Tt; ++t) {
        // (A) prefetch next step's xp (full-step latency hiding)
        float xv2 = 0.f;
        if (tid < HH) {
            int tn = (t + 1 < Tt) ? (t + 1) : (Tt - 1);
            xv2 = xpb[tn * HH + tid];
        }

        // (B) matvec partials: wave-uniform h chunk (broadcast b128 reads)
        float4 h0 = *(const float4*)&h_lds[16 * w + 0];
        float4 h1 = *(const float4*)&h_lds[16 * w + 4];
        float4 h2 = *(const float4*)&h_lds[16 * w + 8];
        float4 h3 = *(const float4*)&h_lds[16 * w + 12];
        float hc[16] = {h0.x, h0.y, h0.z, h0.w, h1.x, h1.y, h1.z, h1.w,
                        h2.x, h2.y, h2.z, h2.w, h3.x, h3.y, h3.z, h3.w};
        float p0 = 0.f, p1 = 0.f, p2 = 0.f, p3 = 0.f;
#pragma unroll
        for (int c = 0; c < 16; ++c) {
            p0 += wreg[0][c] * hc[c];
            p1 += wreg[1][c] * hc[c];
            p2 += wreg[2][c] * hc[c];
            p3 += wreg[3][c] * hc[c];
        }
        *(float4*)&partial[w * PS + 4 * l] = make_float4(p0, p1, p2, p3);
        __syncthreads();

        // (D) reduction lanes: sum 16 partials + xp, tanh, commit h
        if (tid < HH) {
            float s0 = xv, s1 = 0.f, s2 = 0.f, s3 = 0.f;
#pragma unroll
            for (int w2 = 0; w2 < 16; w2 += 4) {
                s0 += partial[(w2 + 0) * PS + tid];
                s1 += partial[(w2 + 1) * PS + tid];
                s2 += partial[(w2 + 2) * PS + tid];
                s3 += partial[(w2 + 3) * PS + tid];
            }
            float hn = tanhf((s0 + s1) + (s2 + s3));
            h_lds[tid] = hn;
            xpb[t * HH + tid] = hn;   // in-place: xp[t] already consumed (xv)
        }
        __syncthreads();
        xv = xv2;
    }
}

// ---------------------------------------------------------------------------
// FC: out[b] = dot(h2[b][T-1][:], W_fc) + b_fc.  One wave per batch.
// ---------------------------------------------------------------------------
__global__ __launch_bounds__(64) void fc_kernel(const float* h2, const float* Wfc,
                                                const float* bfc, float* out)
{
    const int b = blockIdx.x;
    const int l = threadIdx.x;    // 0..63
    const float* hrow = h2 + ((size_t)b * Tt + (Tt - 1)) * HH;
    float4 hv = *(const float4*)&hrow[4 * l];
    float4 wv = *(const float4*)&Wfc[4 * l];
    float p = hv.x * wv.x + hv.y * wv.y + hv.z * wv.z + hv.w * wv.w;
#pragma unroll
    for (int off = 32; off > 0; off >>= 1) p += __shfl_down(p, off, 64);
    if (l == 0) out[b] = p + bfc[0];
}

// ---------------------------------------------------------------------------
extern "C" void kernel_launch(void* const* d_in, const int* in_sizes, int n_in,
                              void* d_out, int out_size, void* d_ws, size_t ws_size,
                              hipStream_t stream)
{
    const float* x     = (const float*)d_in[0];
    const float* W_ih0 = (const float*)d_in[1];
    const float* W_hh0 = (const float*)d_in[2];
    const float* b_ih0 = (const float*)d_in[3];
    const float* b_hh0 = (const float*)d_in[4];
    const float* W_ih1 = (const float*)d_in[5];
    const float* W_hh1 = (const float*)d_in[6];
    const float* b_ih1 = (const float*)d_in[7];
    const float* b_hh1 = (const float*)d_in[8];
    const float* W_fc  = (const float*)d_in[9];
    const float* b_fc  = (const float*)d_in[10];
    float* ws  = (float*)d_ws;                 // B*T*H floats (128 MiB)
    float* out = (float*)d_out;                // 64 floats

    // 1) xp0 = x @ W_ih0^T + b_ih0 + b_hh0
    ih_gemm<INN><<<ROWS / 64, 256, 0, stream>>>(x, W_ih0, b_ih0, b_hh0, ws);
    // 2) layer-0 recurrence (in-place: ws becomes h1 sequence)
    rnn_recur<<<Bb, 1024, 0, stream>>>(ws, W_hh0);
    // 3) xp1 = h1 @ W_ih1^T + b_ih1 + b_hh1   (in-place)
    ih_gemm<HH><<<ROWS / 64, 256, 0, stream>>>(ws, W_ih1, b_ih1, b_hh1, ws);
    // 4) layer-1 recurrence (in-place: ws becomes h2 sequence)
    rnn_recur<<<Bb, 1024, 0, stream>>>(ws, W_hh1);
    // 5) out = h2[:, T-1, :] @ W_fc^T + b_fc
    fc_kernel<<<Bb, 64, 0, stream>>>(ws, W_fc, b_fc, out);
}